// Round 1
// baseline (77.725 us; speedup 1.0000x reference)
//
#include <hip/hip_runtime.h>
#include <hip/hip_bf16.h>

// Problem constants
#define BB 8
#define NN 1024
#define FF 2048
#define CC 4
#define HH 1024
#define ROWS (BB * NN)        // 8192
#define HCHUNKS 16
#define MELEMS (8 * FF)       // 16384 folded weights (channels 0-3: p1, 4-7: p2)

__device__ __forceinline__ float sigmoidf_fast(float x) {
    return __builtin_amdgcn_rcpf(1.0f + __expf(-x));
}

// K1: partial folded weights. Mpart[chunk][j][f] = sum_{h in chunk} W2[c,h] * W1[h, half*F + f]
// j = half*4 + c
__global__ __launch_bounds__(256) void k_fold_partial(const float* __restrict__ W1,
                                                      const float* __restrict__ W2,
                                                      float* __restrict__ Mpart) {
    int k = blockIdx.x * 256 + threadIdx.x;   // 0..4095 over the 2F columns of W1
    int chunk = blockIdx.y;                   // 0..15
    int half = k >> 11;
    int f = k & (FF - 1);
    const float* col = W1 + (size_t)k;        // W1[h, k] at h*4096 + k
    int h0 = chunk * (HH / HCHUNKS);
    float a0 = 0.f, a1 = 0.f, a2 = 0.f, a3 = 0.f;
    #pragma unroll 4
    for (int h = h0; h < h0 + (HH / HCHUNKS); ++h) {
        float wv = col[(size_t)h * (2 * FF)];
        a0 += wv * W2[0 * HH + h];
        a1 += wv * W2[1 * HH + h];
        a2 += wv * W2[2 * HH + h];
        a3 += wv * W2[3 * HH + h];
    }
    float* mp = Mpart + (size_t)chunk * MELEMS + (size_t)(half * 4) * FF + f;
    mp[0 * FF] = a0;
    mp[1 * FF] = a1;
    mp[2 * FF] = a2;
    mp[3 * FF] = a3;
}

// K1b: reduce the 16 partials into M; one extra block computes const[c] = W2[c,:]@b1 + b2[c]
__global__ __launch_bounds__(256) void k_fold_reduce(const float* __restrict__ Mpart,
                                                     const float* __restrict__ W2,
                                                     const float* __restrict__ b1,
                                                     const float* __restrict__ b2,
                                                     float* __restrict__ M,
                                                     float* __restrict__ cst) {
    if (blockIdx.x < 64) {
        int idx = blockIdx.x * 256 + threadIdx.x;   // 0..16383
        float s = 0.f;
        #pragma unroll
        for (int p = 0; p < HCHUNKS; ++p) s += Mpart[(size_t)p * MELEMS + idx];
        M[idx] = s;
    } else {
        int t = threadIdx.x;
        int c = t >> 6, lane = t & 63;
        float s = 0.f;
        for (int h = lane; h < HH; h += 64) s += W2[c * HH + h] * b1[h];
        #pragma unroll
        for (int off = 32; off; off >>= 1) s += __shfl_down(s, off);
        if (lane == 0) cst[c] = s + b2[c];
    }
}

// K2: per-row dots with the 8 folded weight rows + fused copy of vectors to d_out.
// Thread t owns f-slice [8t, 8t+8); weights held in 64 registers.
#define ROWS_PER_BLOCK 8
__global__ __launch_bounds__(256) void k_pcompute(const float* __restrict__ v,
                                                  const float* __restrict__ M,
                                                  float* __restrict__ outv,
                                                  float* __restrict__ P1,
                                                  float* __restrict__ P2) {
    int t = threadIdx.x;
    int f0 = t * 8;
    float w[8][8];
    #pragma unroll
    for (int j = 0; j < 8; ++j) {
        float4 a = *(const float4*)(M + j * FF + f0);
        float4 b = *(const float4*)(M + j * FF + f0 + 4);
        w[j][0] = a.x; w[j][1] = a.y; w[j][2] = a.z; w[j][3] = a.w;
        w[j][4] = b.x; w[j][5] = b.y; w[j][6] = b.z; w[j][7] = b.w;
    }
    __shared__ float red[4 * 8];
    int row0 = blockIdx.x * ROWS_PER_BLOCK;
    for (int r = 0; r < ROWS_PER_BLOCK; ++r) {
        int row = row0 + r;
        const float* vr = v + (size_t)row * FF + f0;
        float4 a = *(const float4*)vr;
        float4 b = *(const float4*)(vr + 4);
        // fused passthrough copy (output 0)
        *(float4*)(outv + (size_t)row * FF + f0) = a;
        *(float4*)(outv + (size_t)row * FF + f0 + 4) = b;
        float x[8] = {a.x, a.y, a.z, a.w, b.x, b.y, b.z, b.w};
        float acc[8];
        #pragma unroll
        for (int j = 0; j < 8; ++j) {
            float s = 0.f;
            #pragma unroll
            for (int k = 0; k < 8; ++k) s += x[k] * w[j][k];
            acc[j] = s;
        }
        #pragma unroll
        for (int j = 0; j < 8; ++j) {
            float s = acc[j];
            #pragma unroll
            for (int off = 32; off; off >>= 1) s += __shfl_down(s, off);
            acc[j] = s;
        }
        int lane = t & 63, wv = t >> 6;
        if (lane == 0) {
            #pragma unroll
            for (int j = 0; j < 8; ++j) red[wv * 8 + j] = acc[j];
        }
        __syncthreads();
        if (t < 8) {
            float s = red[t] + red[8 + t] + red[16 + t] + red[24 + t];
            if (t < 4) P1[t * ROWS + row] = s;
            else       P2[(t - 4) * ROWS + row] = s;
        }
        __syncthreads();
    }
}

// K3: connections[b,c,j,i] = sigmoid(P1[c][b*N+i] + P2[c][b*N+j] + cst[c])
__global__ __launch_bounds__(256) void k_conn(const float* __restrict__ P1,
                                              const float* __restrict__ P2,
                                              const float* __restrict__ cst,
                                              float* __restrict__ out) {
    const int nrows = BB * CC * NN;  // 32768 output rows of length N
    for (int r = blockIdx.x; r < nrows; r += gridDim.x) {
        int b = r >> 12;
        int c = (r >> 10) & 3;
        int j = r & (NN - 1);
        float s = P2[c * ROWS + b * NN + j] + cst[c];
        const float4* p1 = (const float4*)(P1 + c * ROWS + b * NN);
        float4* o = (float4*)(out + (size_t)r * NN);
        int t = threadIdx.x;             // 256 threads x float4 = 1024 = N
        float4 p = p1[t];
        float4 rs;
        rs.x = sigmoidf_fast(p.x + s);
        rs.y = sigmoidf_fast(p.y + s);
        rs.z = sigmoidf_fast(p.z + s);
        rs.w = sigmoidf_fast(p.w + s);
        o[t] = rs;
    }
}

extern "C" void kernel_launch(void* const* d_in, const int* in_sizes, int n_in,
                              void* d_out, int out_size, void* d_ws, size_t ws_size,
                              hipStream_t stream) {
    const float* vectors = (const float*)d_in[0];
    const float* W1 = (const float*)d_in[1];
    const float* b1 = (const float*)d_in[2];
    const float* W2 = (const float*)d_in[3];
    const float* b2 = (const float*)d_in[4];

    float* out_vectors = (float*)d_out;                       // B*N*F = 16777216 floats
    float* out_conn = (float*)d_out + (size_t)ROWS * FF;      // B*C*N*N = 33554432 floats

    float* w = (float*)d_ws;
    float* Mpart = w;                           // 16 * 16384 = 262144 floats
    float* M     = Mpart + HCHUNKS * MELEMS;    // 16384 floats
    float* cst   = M + MELEMS;                  // 4 floats (pad 16)
    float* P1    = cst + 16;                    // C*ROWS = 32768 floats
    float* P2    = P1 + CC * ROWS;              // 32768 floats

    // K1: partial weight fold
    k_fold_partial<<<dim3(16, HCHUNKS), 256, 0, stream>>>(W1, W2, Mpart);
    // K1b: reduce + const
    k_fold_reduce<<<65, 256, 0, stream>>>(Mpart, W2, b1, b2, M, cst);
    // K2: P1/P2 + vectors passthrough
    k_pcompute<<<ROWS / ROWS_PER_BLOCK, 256, 0, stream>>>(vectors, M, out_vectors, P1, P2);
    // K3: connections
    k_conn<<<2048, 256, 0, stream>>>(P1, P2, cst, out_conn);
}